// Round 5
// baseline (10144.748 us; speedup 1.0000x reference)
//
#include <hip/hip_runtime.h>
#include <hip/hip_bf16.h>

typedef __attribute__((ext_vector_type(8))) short bf16x8;
typedef __attribute__((ext_vector_type(4))) float f32x4;
typedef __attribute__((ext_vector_type(4))) unsigned int u32x4;

// Problem sizes (fixed): B=64, L=1024, I=256, H=512
// d_in order: 0 inputs, 1 hidden_states, 2 w_ir, 3 w_iz, 4 w_in, 5 b_ir, 6 b_iz,
//             7 b_in, 8 w_hr, 9 w_hz, 10 w_hn, 11 b_hr, 12 b_hz, 13 b_hn

__device__ __forceinline__ unsigned short f2bf(float f) {
    __hip_bfloat16 h = __float2bfloat16(f);   // RNE
    return __builtin_bit_cast(unsigned short, h);
}
__device__ __forceinline__ float bf2f(unsigned short u) {
    union { unsigned int i; float f; } c; c.i = ((unsigned int)u) << 16; return c.f;
}

// Device-coherent accesses (sc0 sc1 = land at / read from the Infinity-Cache
// coherence point, bypassing the non-coherent per-XCD L2). Each naturally
// aligned DWORD is atomic end-to-end; tiles carry a per-dword tag, so no
// drain/ordering is needed between a tile store and its hint-flag store.
__device__ __forceinline__ void store_tile16(u32x4* p, u32x4 v) {
    asm volatile("global_store_dwordx4 %0, %1, off sc0 sc1" :: "v"(p), "v"(v) : "memory");
}
__device__ __forceinline__ void store_flag(unsigned int* p, unsigned int v) {
    asm volatile("global_store_dword %0, %1, off sc0 sc1" :: "v"(p), "v"(v) : "memory");
}
__device__ __forceinline__ void lds_drain() {
    asm volatile("s_waitcnt lgkmcnt(0)" ::: "memory");
}

// ---------------------------------------------------------------- pack inputs
// fp32 [64][1024][256] -> bf16 (rows m = b*1024+t are contiguous I=256)
__global__ void pack_inputs(const float* __restrict__ in, unsigned short* __restrict__ out) {
    int i = blockIdx.x * 256 + threadIdx.x;          // 16384 blocks: i < 4194304
    float4 v = reinterpret_cast<const float4*>(in)[i];
    ushort4 u;
    u.x = f2bf(v.x); u.y = f2bf(v.y); u.z = f2bf(v.z); u.w = f2bf(v.w);
    reinterpret_cast<ushort4*>(out)[i] = u;
}

// ---------------------------------------------------------------- pack weights
// Wx  bf16 [1536][256]  (n = g*512 + j; g: 0=r,1=z,2=n)
// Wh  bf16 [3][512][512]
// biasx fp32 [1536]: r: b_ir+b_hr, z: b_iz+b_hz, n: b_in (b_hn inside r*(...))
// Also zero-inits the tagged tile buffer (tag 0 != any live tag >= 1) and the
// 128 hint flags (ws is re-poisoned every call; kernel-end L2 writeback
// publishes the zeros to the coherence point).
__global__ void pack_weights(const float* __restrict__ w_ir, const float* __restrict__ w_iz,
                             const float* __restrict__ w_in, const float* __restrict__ b_ir,
                             const float* __restrict__ b_iz, const float* __restrict__ b_in,
                             const float* __restrict__ w_hr, const float* __restrict__ w_hz,
                             const float* __restrict__ w_hn, const float* __restrict__ b_hr,
                             const float* __restrict__ b_hz,
                             unsigned short* __restrict__ Wx, unsigned short* __restrict__ Wh,
                             float* __restrict__ biasx, unsigned int* __restrict__ Hp,
                             unsigned int* __restrict__ flags) {
    int i = blockIdx.x * 256 + threadIdx.x;          // 3072 blocks: i < 786432
    {
        int g = i / 262144, rem = i % 262144;
        const float* src = (g == 0) ? w_hr : ((g == 1) ? w_hz : w_hn);
        Wh[i] = f2bf(src[rem]);
    }
    if (i < 393216) {
        int g = i / 131072, rem = i % 131072;
        const float* src = (g == 0) ? w_ir : ((g == 1) ? w_iz : w_in);
        Wx[i] = f2bf(src[rem]);
    }
    if (i < 1536) {
        int g = i / 512, j = i % 512;
        float v = (g == 0) ? (b_ir[j] + b_hr[j]) : ((g == 1) ? (b_iz[j] + b_hz[j]) : b_in[j]);
        biasx[i] = v;
    }
    if (i < 65536) Hp[i] = 0u;     // [2][4][32][256] tagged dwords
    if (i < 4096) flags[i] = 0u;   // 128 flags x 32 dwords (128 B lines)
}

// ---------------------------------------------------------------- input projection GEMM
// C[m][n] = sum_k A[m][k]*Wx[n][k] + biasx[n],  M=65536, N=1536, K=256
// written as bf16 X[t][b][n] with t = m & 1023, b = m >> 10.
__global__ __launch_bounds__(256) void xproj_gemm(
    const unsigned short* __restrict__ A,    // [65536][256] bf16
    const unsigned short* __restrict__ Bw,   // [1536][256]  bf16
    const float* __restrict__ biasx,         // [1536]
    unsigned short* __restrict__ X)          // [1024][64][1536] bf16
{
    __shared__ __attribute__((aligned(16))) unsigned short Al[64][40]; // +8 pad
    __shared__ __attribute__((aligned(16))) unsigned short Bl[64][40];
    const int tid  = threadIdx.x;
    const int m0   = blockIdx.x * 64;
    const int n0   = blockIdx.y * 64;
    const int lane = tid & 63;
    const int wv   = tid >> 6;
    const int quad = lane >> 4;
    const int l16  = lane & 15;
    const int mw   = (wv & 1) * 32;
    const int nw   = (wv >> 1) * 32;
    const int lr   = tid >> 2;          // 0..63 staging row
    const int lc   = (tid & 3) * 8;     // k offset within BK=32

    f32x4 acc[2][2] = {};

    for (int kb = 0; kb < 8; ++kb) {
        uint4 av = *reinterpret_cast<const uint4*>(A  + (size_t)(m0 + lr) * 256 + kb * 32 + lc);
        uint4 bv = *reinterpret_cast<const uint4*>(Bw + (size_t)(n0 + lr) * 256 + kb * 32 + lc);
        __syncthreads();
        *reinterpret_cast<uint4*>(&Al[lr][lc]) = av;
        *reinterpret_cast<uint4*>(&Bl[lr][lc]) = bv;
        __syncthreads();
        bf16x8 af[2], bfg[2];
#pragma unroll
        for (int s = 0; s < 2; ++s) {
            af[s]  = *reinterpret_cast<const bf16x8*>(&Al[mw + s * 16 + l16][quad * 8]);
            bfg[s] = *reinterpret_cast<const bf16x8*>(&Bl[nw + s * 16 + l16][quad * 8]);
        }
#pragma unroll
        for (int sm = 0; sm < 2; ++sm)
#pragma unroll
            for (int sn = 0; sn < 2; ++sn)
                acc[sm][sn] = __builtin_amdgcn_mfma_f32_16x16x32_bf16(af[sm], bfg[sn], acc[sm][sn], 0, 0, 0);
    }
    // epilogue: D layout col = lane&15 (n), row = quad*4 + r (m)
#pragma unroll
    for (int sn = 0; sn < 2; ++sn) {
        int n = n0 + nw + sn * 16 + l16;
        float bias = biasx[n];
#pragma unroll
        for (int sm = 0; sm < 2; ++sm)
#pragma unroll
            for (int r = 0; r < 4; ++r) {
                int m = m0 + mw + sm * 16 + quad * 4 + r;
                int t = m & 1023, b = m >> 10;
                X[(size_t)(t * 64 + b) * 1536 + n] = f2bf(acc[sm][sn][r] + bias);
            }
    }
}

// ---------------------------------------------------------------- recurrent scan
// 32 workgroups x 512 threads (8 waves), 1 block/CU co-resident. Block bid
// owns output dims [bid*16, bid*16+16) per gate. Wave wv = mg + 4*kh: batch
// rows [mg*16, mg*16+16), k-half kh. Weight B-fragments: 96 VGPR/lane,
// register-resident for all 1024 steps.
//
// SELF-VALIDATING COALESCED TILE EXCHANGE: h lives in Hp as 1KB tiles of
// tagged dwords  T[brow16][jcol16] = (tag<<16)|bf16(h),  slot = t&1,
// tag = (t>>1)+1. Producer wave (kh0, block bid, plane mg) transposes its
// 16x16 h-tile through LDS (intra-wave, lgkmcnt only) and publishes it with
// ONE global_store_dwordx4 per lane (contiguous 1KB wave-store), then its
// hint flag immediately — NO vmcnt drain anywhere: per-dword atomicity +
// embedded tags make flag/data ordering irrelevant. Consumers SPECULATIVELY
// load their A-data (coalesced 2KB runs) and tag-check; only on mismatch do
// they fall back to the cheap flag poll and reload (bounded — no round-2
// data-spin). A failing tag can only mean "too early", never "overwritten":
// the round-4 induction (flags stored after the block-wide barrier certify
// every reader of step t-1 finished before slot (t+1)&1 is overwritten)
// is unchanged. ONE __syncthreads per step (red ping-pongs on t&1).
__global__ __launch_bounds__(512, 1) void gru_scan(
    const unsigned short* __restrict__ X,    // [1024][64][1536] bf16 (biases folded)
    const unsigned short* __restrict__ Wh,   // [3][512][512] bf16
    const float* __restrict__ h0,            // [1][64][512]
    const float* __restrict__ b_hn,          // [512]
    unsigned int* __restrict__ Hp,           // [2][4 mg][32 ktile][256] tagged dwords
    unsigned int* __restrict__ flags,        // [128*32] (zeroed by pack_weights)
    float* __restrict__ out)                 // [64][1024][512] fp32, then hlast [64][512]
{
    const int tid  = threadIdx.x;
    const int lane = tid & 63;
    const int wv   = tid >> 6;      // wave 0..7
    const int mg   = wv & 3;        // batch-row plane: rows mg*16 .. mg*16+15
    const int kh   = wv >> 2;       // k-half: 0 -> [0,256), 1 -> [256,512)
    const int quad = lane >> 4;
    const int jl   = lane & 15;
    const int bid  = blockIdx.x;    // 0..31
    const int jg   = bid * 16 + jl; // this lane's output dim (per gate)

    __shared__ __attribute__((aligned(16))) f32x4 red[2][3][4][64];   // 24576 B
    __shared__ __attribute__((aligned(16))) unsigned int tsc[4][256]; // 4096 B transpose scratch

    // Weight B-fragments for this k-half: lane jl holds row j=jg,
    // k = kh*256 + kk*32 + quad*8 + (0..7) -> contiguous 16B from Wh[g][jg][...]
    bf16x8 bfrag[3][8];
#pragma unroll
    for (int g = 0; g < 3; ++g)
#pragma unroll
        for (int kk = 0; kk < 8; ++kk) {
            uint4 v = *reinterpret_cast<const uint4*>(
                Wh + (size_t)(g * 512 + jg) * 512 + kh * 256 + kk * 32 + quad * 8);
            bfrag[g][kk] = __builtin_bit_cast(bf16x8, v);
        }
    const float bhn = b_hn[jg];

    unsigned int* const flag_my = flags + (bid * 4 + mg) * 32;
    const unsigned int* const fpoll = flags + ((kh * 16 + jl) * 4 + mg) * 32;

    // init: kh0 waves publish tagged h0 tiles (slot 0, tag 1) + hint flag.
    float h_reg[4];
    float xv[3][4];
    if (kh == 0) {
#pragma unroll
        for (int r = 0; r < 4; ++r) {
            int b = mg * 16 + quad * 4 + r;
            float h = h0[b * 512 + jg];
            h_reg[r] = h;
            tsc[mg][(quad * 4 + r) * 16 + jl] = (1u << 16) | (unsigned int)f2bf(h);
        }
        lds_drain();   // intra-wave cross-lane transpose: lgkmcnt(0) suffices
        {
            u32x4 tv = *reinterpret_cast<const u32x4*>(&tsc[mg][lane * 4]);
            store_tile16(reinterpret_cast<u32x4*>(Hp + (size_t)(mg * 32 + bid) * 256 + lane * 4), tv);
        }
        if (lane == 0) store_flag(flag_my, 1u);   // hint only — no drain
        // preload x projections for t=0 (off the critical path)
#pragma unroll
        for (int r = 0; r < 4; ++r) {
            int b = mg * 16 + quad * 4 + r;
#pragma unroll
            for (int g = 0; g < 3; ++g)
                xv[g][r] = bf2f(X[(size_t)b * 1536 + g * 512 + jg]);
        }
    }

    // consumer u64 base: slot stride 16384, plane stride 4096, tile stride 128.
    // lane (quad,jl) reads A[brow=mg*16+jl][j = kh*256 + kk*32 + quad*8 ..+7]:
    // tile = kh*16 + kk*2 + (quad>>1), u64 off = jl*8 + (quad&1)*4 + p(0..3).
    const unsigned long long* hb = reinterpret_cast<const unsigned long long*>(Hp);
    const int lbase = mg * 4096 + (kh * 16 + (quad >> 1)) * 128 + jl * 8 + (quad & 1) * 4;

    for (int t = 0; t < 1024; ++t) {
        const int cur = t & 1;
        const unsigned int tag  = (unsigned int)((t >> 1) + 1);
        const unsigned int tag2 = tag | (tag << 16);
        const unsigned long long* hs = hb + (size_t)cur * 16384 + lbase;

        unsigned long long w[32];
        auto loadchk = [&]() -> unsigned int {
            unsigned int e = 0u;
#pragma unroll
            for (int kk = 0; kk < 8; ++kk)
#pragma unroll
                for (int p = 0; p < 4; ++p) {
                    unsigned long long ww = __hip_atomic_load(
                        hs + kk * 256 + p, __ATOMIC_RELAXED, __HIP_MEMORY_SCOPE_AGENT);
                    w[kk * 4 + p] = ww;
                    unsigned int hi = ((unsigned int)(ww >> 16) & 0xFFFFu) |
                                      ((unsigned int)(ww >> 48) << 16);
                    e |= hi ^ tag2;
                }
            return e;
        };
        // speculative pass (overlaps producer propagation); flag-gated fallback
        unsigned int err = loadchk();
        if (!__all(err == 0u)) {
            const unsigned int tgt = (unsigned int)(t + 1);
            unsigned int v;
            do { v = __hip_atomic_load(fpoll, __ATOMIC_RELAXED, __HIP_MEMORY_SCOPE_AGENT); }
            while (!__all((int)(v >= tgt)));
            do { err = loadchk(); } while (!__all(err == 0u));
        }

        // unpack tagged dwords -> bf16x8 A-fragments
        bf16x8 afrag[8];
#pragma unroll
        for (int kk = 0; kk < 8; ++kk) {
            uint4 u;
            unsigned long long w0 = w[kk * 4 + 0], w1 = w[kk * 4 + 1];
            unsigned long long w2 = w[kk * 4 + 2], w3 = w[kk * 4 + 3];
            u.x = ((unsigned int)w0 & 0xFFFFu) | (((unsigned int)(w0 >> 32)) << 16);
            u.y = ((unsigned int)w1 & 0xFFFFu) | (((unsigned int)(w1 >> 32)) << 16);
            u.z = ((unsigned int)w2 & 0xFFFFu) | (((unsigned int)(w2 >> 32)) << 16);
            u.w = ((unsigned int)w3 & 0xFFFFu) | (((unsigned int)(w3 >> 32)) << 16);
            afrag[kk] = __builtin_bit_cast(bf16x8, u);
        }

        f32x4 acc[3];
#pragma unroll
        for (int g = 0; g < 3; ++g) {
            f32x4 a = {0.f, 0.f, 0.f, 0.f};
#pragma unroll
            for (int kk = 0; kk < 8; ++kk)
                a = __builtin_amdgcn_mfma_f32_16x16x32_bf16(afrag[kk], bfrag[g][kk], a, 0, 0, 0);
            acc[g] = a;
        }

        if (kh == 1) {
#pragma unroll
            for (int g = 0; g < 3; ++g)
                red[cur][g][mg][lane] = acc[g];
        }
        __syncthreads();   // the ONLY barrier per step (red ping-pongs on t&1)

        if (kh == 0) {
#pragma unroll
            for (int g = 0; g < 3; ++g)
                acc[g] += red[cur][g][mg][lane];

            const unsigned int ntag = (unsigned int)((((unsigned int)(t + 1)) >> 1) + 1) << 16;
#pragma unroll
            for (int r = 0; r < 4; ++r) {
                float rv = 1.f / (1.f + __expf(-(xv[0][r] + acc[0][r])));
                float zv = 1.f / (1.f + __expf(-(xv[1][r] + acc[1][r])));
                float na = xv[2][r] + rv * (acc[2][r] + bhn);
                float nv = 1.f - 2.f / (1.f + __expf(2.f * na));   // tanh, inf-safe
                float h  = (1.f - zv) * nv + zv * h_reg[r];
                h_reg[r] = h;
                tsc[mg][(quad * 4 + r) * 16 + jl] = ntag | (unsigned int)f2bf(h);
            }
            if (t < 1023) {
                lds_drain();   // intra-wave transpose complete
                u32x4 tv = *reinterpret_cast<const u32x4*>(&tsc[mg][lane * 4]);
                store_tile16(reinterpret_cast<u32x4*>(
                    Hp + ((size_t)(((t + 1) & 1) * 4 + mg) * 32 + bid) * 256 + lane * 4), tv);
                if (lane == 0) store_flag(flag_my, (unsigned int)(t + 2));  // hint, no drain
            }
            // out stores (plain, cached) — off the critical path
#pragma unroll
            for (int r = 0; r < 4; ++r) {
                int b = mg * 16 + quad * 4 + r;
                out[(size_t)b * (1024 * 512) + (size_t)t * 512 + jg] = h_reg[r];
            }
            if (t < 1023) {
                // prefetch next step's x projections; complete during next wait
                const unsigned short* Xt = X + (size_t)(t + 1) * (64 * 1536);
#pragma unroll
                for (int r = 0; r < 4; ++r) {
                    int b = mg * 16 + quad * 4 + r;
#pragma unroll
                    for (int g = 0; g < 3; ++g)
                        xv[g][r] = bf2f(Xt[b * 1536 + g * 512 + jg]);
                }
            } else {
#pragma unroll
                for (int r = 0; r < 4; ++r) {
                    int b = mg * 16 + quad * 4 + r;
                    out[(size_t)(64 * 1024 * 512) + b * 512 + jg] = h_reg[r];
                }
            }
        }
    }
}

// ---------------------------------------------------------------- host
extern "C" void kernel_launch(void* const* d_in, const int* in_sizes, int n_in,
                              void* d_out, int out_size, void* d_ws, size_t ws_size,
                              hipStream_t stream) {
    const float* inputs = (const float*)d_in[0];
    const float* h0     = (const float*)d_in[1];
    const float* w_ir   = (const float*)d_in[2];
    const float* w_iz   = (const float*)d_in[3];
    const float* w_in   = (const float*)d_in[4];
    const float* b_ir   = (const float*)d_in[5];
    const float* b_iz   = (const float*)d_in[6];
    const float* b_in   = (const float*)d_in[7];
    const float* w_hr   = (const float*)d_in[8];
    const float* w_hz   = (const float*)d_in[9];
    const float* w_hn   = (const float*)d_in[10];
    const float* b_hr   = (const float*)d_in[11];
    const float* b_hz   = (const float*)d_in[12];
    const float* b_hn   = (const float*)d_in[13];
    float* out = (float*)d_out;

    // ws layout (16B aligned)
    char* wsb = (char*)d_ws;
    unsigned short* X     = (unsigned short*)(wsb);              // 201326592 B
    unsigned short* Abf   = (unsigned short*)(wsb + 201326592);  //  33554432 B
    unsigned short* Wx    = (unsigned short*)(wsb + 234881024);  //    786432 B
    unsigned short* Wh    = (unsigned short*)(wsb + 235667456);  //   1572864 B
    float*          biasx = (float*)        (wsb + 237240320);   //      6144 B
    unsigned int*   Hp    = (unsigned int*) (wsb + 237246464);   //    262144 B
    unsigned int*   flags = (unsigned int*) (wsb + 237508608);   //     16384 B (end 237524992)

    pack_inputs<<<16384, 256, 0, stream>>>(inputs, Abf);
    pack_weights<<<3072, 256, 0, stream>>>(w_ir, w_iz, w_in, b_ir, b_iz, b_in,
                                           w_hr, w_hz, w_hn, b_hr, b_hz, Wx, Wh, biasx, Hp, flags);
    xproj_gemm<<<dim3(1024, 24), 256, 0, stream>>>(Abf, Wx, biasx, X);
    gru_scan<<<32, 512, 0, stream>>>(X, Wh, h0, b_hn, Hp, flags, out);
}

// Round 6
// 8906.824 us; speedup vs baseline: 1.1390x; 1.1390x over previous
//
#include <hip/hip_runtime.h>
#include <hip/hip_bf16.h>

typedef __attribute__((ext_vector_type(8))) short bf16x8;
typedef __attribute__((ext_vector_type(4))) float f32x4;
typedef __attribute__((ext_vector_type(4))) unsigned int u32x4;

// Problem sizes (fixed): B=64, L=1024, I=256, H=512
// d_in order: 0 inputs, 1 hidden_states, 2 w_ir, 3 w_iz, 4 w_in, 5 b_ir, 6 b_iz,
//             7 b_in, 8 w_hr, 9 w_hz, 10 w_hn, 11 b_hr, 12 b_hz, 13 b_hn

__device__ __forceinline__ unsigned short f2bf(float f) {
    __hip_bfloat16 h = __float2bfloat16(f);   // RNE
    return __builtin_bit_cast(unsigned short, h);
}
__device__ __forceinline__ float bf2f(unsigned short u) {
    union { unsigned int i; float f; } c; c.i = ((unsigned int)u) << 16; return c.f;
}

// Device-coherent accesses (sc0 sc1 = land at / read from the Infinity-Cache
// coherence point, bypassing the non-coherent per-XCD L2). Each naturally
// aligned DWORD is atomic end-to-end; tiles carry a per-dword tag, so NO
// vmcnt drain is needed between a tile store and its hint-flag store: a
// flag that leads its data only causes a tag-detected bounded retry.
__device__ __forceinline__ void store_tile16(u32x4* p, u32x4 v) {
    asm volatile("global_store_dwordx4 %0, %1, off sc0 sc1" :: "v"(p), "v"(v) : "memory");
}
__device__ __forceinline__ void store_flag(unsigned int* p, unsigned int v) {
    asm volatile("global_store_dword %0, %1, off sc0 sc1" :: "v"(p), "v"(v) : "memory");
}
__device__ __forceinline__ void lds_drain() {
    asm volatile("s_waitcnt lgkmcnt(0)" ::: "memory");
}

// ---------------------------------------------------------------- pack inputs
// fp32 [64][1024][256] -> bf16 (rows m = b*1024+t are contiguous I=256)
__global__ void pack_inputs(const float* __restrict__ in, unsigned short* __restrict__ out) {
    int i = blockIdx.x * 256 + threadIdx.x;          // 16384 blocks: i < 4194304
    float4 v = reinterpret_cast<const float4*>(in)[i];
    ushort4 u;
    u.x = f2bf(v.x); u.y = f2bf(v.y); u.z = f2bf(v.z); u.w = f2bf(v.w);
    reinterpret_cast<ushort4*>(out)[i] = u;
}

// ---------------------------------------------------------------- pack weights
// Wx  bf16 [1536][256]  (n = g*512 + j; g: 0=r,1=z,2=n)
// Wh  bf16 [3][512][512]
// biasx fp32 [1536]: r: b_ir+b_hr, z: b_iz+b_hz, n: b_in (b_hn inside r*(...))
// Also zero-inits the tagged tile buffer (tag 0 != any live tag >= 1) and the
// 128 hint flags (ws is re-poisoned every call; kernel-end L2 writeback
// publishes the zeros to the coherence point).
__global__ void pack_weights(const float* __restrict__ w_ir, const float* __restrict__ w_iz,
                             const float* __restrict__ w_in, const float* __restrict__ b_ir,
                             const float* __restrict__ b_iz, const float* __restrict__ b_in,
                             const float* __restrict__ w_hr, const float* __restrict__ w_hz,
                             const float* __restrict__ w_hn, const float* __restrict__ b_hr,
                             const float* __restrict__ b_hz,
                             unsigned short* __restrict__ Wx, unsigned short* __restrict__ Wh,
                             float* __restrict__ biasx, unsigned int* __restrict__ Hp,
                             unsigned int* __restrict__ flags) {
    int i = blockIdx.x * 256 + threadIdx.x;          // 3072 blocks: i < 786432
    {
        int g = i / 262144, rem = i % 262144;
        const float* src = (g == 0) ? w_hr : ((g == 1) ? w_hz : w_hn);
        Wh[i] = f2bf(src[rem]);
    }
    if (i < 393216) {
        int g = i / 131072, rem = i % 131072;
        const float* src = (g == 0) ? w_ir : ((g == 1) ? w_iz : w_in);
        Wx[i] = f2bf(src[rem]);
    }
    if (i < 1536) {
        int g = i / 512, j = i % 512;
        float v = (g == 0) ? (b_ir[j] + b_hr[j]) : ((g == 1) ? (b_iz[j] + b_hz[j]) : b_in[j]);
        biasx[i] = v;
    }
    if (i < 65536) Hp[i] = 0u;     // [2][4][32][256] tagged dwords
    if (i < 4096) flags[i] = 0u;   // 128 flags x 32 dwords (128 B lines)
}

// ---------------------------------------------------------------- input projection GEMM
// C[m][n] = sum_k A[m][k]*Wx[n][k] + biasx[n],  M=65536, N=1536, K=256
// written as bf16 X[t][b][n] with t = m & 1023, b = m >> 10.
__global__ __launch_bounds__(256) void xproj_gemm(
    const unsigned short* __restrict__ A,    // [65536][256] bf16
    const unsigned short* __restrict__ Bw,   // [1536][256]  bf16
    const float* __restrict__ biasx,         // [1536]
    unsigned short* __restrict__ X)          // [1024][64][1536] bf16
{
    __shared__ __attribute__((aligned(16))) unsigned short Al[64][40]; // +8 pad
    __shared__ __attribute__((aligned(16))) unsigned short Bl[64][40];
    const int tid  = threadIdx.x;
    const int m0   = blockIdx.x * 64;
    const int n0   = blockIdx.y * 64;
    const int lane = tid & 63;
    const int wv   = tid >> 6;
    const int quad = lane >> 4;
    const int l16  = lane & 15;
    const int mw   = (wv & 1) * 32;
    const int nw   = (wv >> 1) * 32;
    const int lr   = tid >> 2;          // 0..63 staging row
    const int lc   = (tid & 3) * 8;     // k offset within BK=32

    f32x4 acc[2][2] = {};

    for (int kb = 0; kb < 8; ++kb) {
        uint4 av = *reinterpret_cast<const uint4*>(A  + (size_t)(m0 + lr) * 256 + kb * 32 + lc);
        uint4 bv = *reinterpret_cast<const uint4*>(Bw + (size_t)(n0 + lr) * 256 + kb * 32 + lc);
        __syncthreads();
        *reinterpret_cast<uint4*>(&Al[lr][lc]) = av;
        *reinterpret_cast<uint4*>(&Bl[lr][lc]) = bv;
        __syncthreads();
        bf16x8 af[2], bfg[2];
#pragma unroll
        for (int s = 0; s < 2; ++s) {
            af[s]  = *reinterpret_cast<const bf16x8*>(&Al[mw + s * 16 + l16][quad * 8]);
            bfg[s] = *reinterpret_cast<const bf16x8*>(&Bl[nw + s * 16 + l16][quad * 8]);
        }
#pragma unroll
        for (int sm = 0; sm < 2; ++sm)
#pragma unroll
            for (int sn = 0; sn < 2; ++sn)
                acc[sm][sn] = __builtin_amdgcn_mfma_f32_16x16x32_bf16(af[sm], bfg[sn], acc[sm][sn], 0, 0, 0);
    }
    // epilogue: D layout col = lane&15 (n), row = quad*4 + r (m)
#pragma unroll
    for (int sn = 0; sn < 2; ++sn) {
        int n = n0 + nw + sn * 16 + l16;
        float bias = biasx[n];
#pragma unroll
        for (int sm = 0; sm < 2; ++sm)
#pragma unroll
            for (int r = 0; r < 4; ++r) {
                int m = m0 + mw + sm * 16 + quad * 4 + r;
                int t = m & 1023, b = m >> 10;
                X[(size_t)(t * 64 + b) * 1536 + n] = f2bf(acc[sm][sn][r] + bias);
            }
    }
}

// ---------------------------------------------------------------- recurrent scan
// 32 workgroups x 512 threads (8 waves), 1 block/CU co-resident. Block bid
// owns output dims [bid*16, bid*16+16) per gate. Wave wv = mg + 4*kh: batch
// rows [mg*16, mg*16+16), k-half kh. Weight B-fragments: 96 VGPR/lane,
// register-resident for all 1024 steps.
//
// PROTOCOL (round-4 shape, minus the producer ack-drain):
//   Producer wave (kh0, plane mg of block bid): transpose 16x16 h-tile through
//   LDS (intra-wave, lgkmcnt only) into TAGGED dwords (tag<<16)|bf16(h),
//   slot=t&1, tag=(t>>1)+1; publish with ONE global_store_dwordx4 per lane
//   (contiguous 1KB wave-store); store the hint flag IMMEDIATELY — no vmcnt
//   drain (saves ~1 coherence round trip per step). Per-dword atomicity +
//   embedded tags make flag/data ordering harmless.
//   Consumer: spin on its 16 hint flags FIRST (cheap 4B poll — round-5 lesson:
//   consumers always arrive early, so a speculative data load is a guaranteed
//   miss that serializes an extra ~1.5 RT; never load data before the flag),
//   then load A-data (coalesced 2KB runs) and tag-verify with bounded retry
//   (retry only if the flag beat its data through the fabric).
// Overwrite safety: unchanged round-4/5 induction — flags are stored after
// the block-wide barrier, so flag >= t+2 certifies every reader of step-t
// data in that block finished; slot (t&1) is only rewritten 2 steps later.
// A failing tag can only mean "too early", never "overwritten".
// ONE __syncthreads per step (red ping-pongs on t&1).
__global__ __launch_bounds__(512, 1) void gru_scan(
    const unsigned short* __restrict__ X,    // [1024][64][1536] bf16 (biases folded)
    const unsigned short* __restrict__ Wh,   // [3][512][512] bf16
    const float* __restrict__ h0,            // [1][64][512]
    const float* __restrict__ b_hn,          // [512]
    unsigned int* __restrict__ Hp,           // [2][4 mg][32 ktile][256] tagged dwords
    unsigned int* __restrict__ flags,        // [128*32] (zeroed by pack_weights)
    float* __restrict__ out)                 // [64][1024][512] fp32, then hlast [64][512]
{
    const int tid  = threadIdx.x;
    const int lane = tid & 63;
    const int wv   = tid >> 6;      // wave 0..7
    const int mg   = wv & 3;        // batch-row plane: rows mg*16 .. mg*16+15
    const int kh   = wv >> 2;       // k-half: 0 -> [0,256), 1 -> [256,512)
    const int quad = lane >> 4;
    const int jl   = lane & 15;
    const int bid  = blockIdx.x;    // 0..31
    const int jg   = bid * 16 + jl; // this lane's output dim (per gate)

    __shared__ __attribute__((aligned(16))) f32x4 red[2][3][4][64];   // 24576 B
    __shared__ __attribute__((aligned(16))) unsigned int tsc[4][256]; // 4096 B transpose scratch

    // Weight B-fragments for this k-half: lane jl holds row j=jg,
    // k = kh*256 + kk*32 + quad*8 + (0..7) -> contiguous 16B from Wh[g][jg][...]
    bf16x8 bfrag[3][8];
#pragma unroll
    for (int g = 0; g < 3; ++g)
#pragma unroll
        for (int kk = 0; kk < 8; ++kk) {
            uint4 v = *reinterpret_cast<const uint4*>(
                Wh + (size_t)(g * 512 + jg) * 512 + kh * 256 + kk * 32 + quad * 8);
            bfrag[g][kk] = __builtin_bit_cast(bf16x8, v);
        }
    const float bhn = b_hn[jg];

    unsigned int* const flag_my = flags + (bid * 4 + mg) * 32;
    const unsigned int* const fpoll = flags + ((kh * 16 + jl) * 4 + mg) * 32;

    // init: kh0 waves publish tagged h0 tiles (slot 0, tag 1) + hint flag.
    float h_reg[4];
    float xv[3][4];
    if (kh == 0) {
#pragma unroll
        for (int r = 0; r < 4; ++r) {
            int b = mg * 16 + quad * 4 + r;
            float h = h0[b * 512 + jg];
            h_reg[r] = h;
            tsc[mg][(quad * 4 + r) * 16 + jl] = (1u << 16) | (unsigned int)f2bf(h);
        }
        lds_drain();   // intra-wave cross-lane transpose: lgkmcnt(0) suffices
        {
            u32x4 tv = *reinterpret_cast<const u32x4*>(&tsc[mg][lane * 4]);
            store_tile16(reinterpret_cast<u32x4*>(Hp + (size_t)(mg * 32 + bid) * 256 + lane * 4), tv);
        }
        if (lane == 0) store_flag(flag_my, 1u);   // no drain: tags protect
        // preload x projections for t=0 (off the critical path)
#pragma unroll
        for (int r = 0; r < 4; ++r) {
            int b = mg * 16 + quad * 4 + r;
#pragma unroll
            for (int g = 0; g < 3; ++g)
                xv[g][r] = bf2f(X[(size_t)b * 1536 + g * 512 + jg]);
        }
    }

    // consumer u64 base: slot stride 16384, plane stride 4096, tile stride 128.
    // lane (quad,jl) reads A[brow=mg*16+jl][j = kh*256 + kk*32 + quad*8 ..+7]:
    // tile = kh*16 + kk*2 + (quad>>1), u64 off = jl*8 + (quad&1)*4 + p(0..3).
    const unsigned long long* hb = reinterpret_cast<const unsigned long long*>(Hp);
    const int lbase = mg * 4096 + (kh * 16 + (quad >> 1)) * 128 + jl * 8 + (quad & 1) * 4;

    for (int t = 0; t < 1024; ++t) {
        const int cur = t & 1;
        const unsigned int tag  = (unsigned int)((t >> 1) + 1);
        const unsigned int tag2 = tag | (tag << 16);
        const unsigned long long* hs = hb + (size_t)cur * 16384 + lbase;

        // ---- wait: hint flags FIRST (consumers always arrive early; 4B spin)
        {
            const unsigned int tgt = (unsigned int)(t + 1);
            unsigned int v;
            do { v = __hip_atomic_load(fpoll, __ATOMIC_RELAXED, __HIP_MEMORY_SCOPE_AGENT); }
            while (!__all((int)(v >= tgt)));
        }

        // ---- load + tag-verify (bounded retry: only if flag beat its data)
        unsigned long long w[32];
        unsigned int err;
        do {
            err = 0u;
#pragma unroll
            for (int kk = 0; kk < 8; ++kk)
#pragma unroll
                for (int p = 0; p < 4; ++p) {
                    unsigned long long ww = __hip_atomic_load(
                        hs + kk * 256 + p, __ATOMIC_RELAXED, __HIP_MEMORY_SCOPE_AGENT);
                    w[kk * 4 + p] = ww;
                    unsigned int hi = ((unsigned int)(ww >> 16) & 0xFFFFu) |
                                      ((unsigned int)(ww >> 48) << 16);
                    err |= hi ^ tag2;
                }
        } while (!__all(err == 0u));

        // unpack tagged dwords -> bf16x8 A-fragments
        bf16x8 afrag[8];
#pragma unroll
        for (int kk = 0; kk < 8; ++kk) {
            uint4 u;
            unsigned long long w0 = w[kk * 4 + 0], w1 = w[kk * 4 + 1];
            unsigned long long w2 = w[kk * 4 + 2], w3 = w[kk * 4 + 3];
            u.x = ((unsigned int)w0 & 0xFFFFu) | (((unsigned int)(w0 >> 32)) << 16);
            u.y = ((unsigned int)w1 & 0xFFFFu) | (((unsigned int)(w1 >> 32)) << 16);
            u.z = ((unsigned int)w2 & 0xFFFFu) | (((unsigned int)(w2 >> 32)) << 16);
            u.w = ((unsigned int)w3 & 0xFFFFu) | (((unsigned int)(w3 >> 32)) << 16);
            afrag[kk] = __builtin_bit_cast(bf16x8, u);
        }

        f32x4 acc[3];
#pragma unroll
        for (int g = 0; g < 3; ++g) {
            f32x4 a = {0.f, 0.f, 0.f, 0.f};
#pragma unroll
            for (int kk = 0; kk < 8; ++kk)
                a = __builtin_amdgcn_mfma_f32_16x16x32_bf16(afrag[kk], bfrag[g][kk], a, 0, 0, 0);
            acc[g] = a;
        }

        if (kh == 1) {
#pragma unroll
            for (int g = 0; g < 3; ++g)
                red[cur][g][mg][lane] = acc[g];
        }
        __syncthreads();   // the ONLY barrier per step (red ping-pongs on t&1)

        if (kh == 0) {
#pragma unroll
            for (int g = 0; g < 3; ++g)
                acc[g] += red[cur][g][mg][lane];

            const unsigned int ntag = (unsigned int)((((unsigned int)(t + 1)) >> 1) + 1) << 16;
#pragma unroll
            for (int r = 0; r < 4; ++r) {
                float rv = 1.f / (1.f + __expf(-(xv[0][r] + acc[0][r])));
                float zv = 1.f / (1.f + __expf(-(xv[1][r] + acc[1][r])));
                float na = xv[2][r] + rv * (acc[2][r] + bhn);
                float nv = 1.f - 2.f / (1.f + __expf(2.f * na));   // tanh, inf-safe
                float h  = (1.f - zv) * nv + zv * h_reg[r];
                h_reg[r] = h;
                tsc[mg][(quad * 4 + r) * 16 + jl] = ntag | (unsigned int)f2bf(h);
            }
            if (t < 1023) {
                lds_drain();   // intra-wave transpose complete
                u32x4 tv = *reinterpret_cast<const u32x4*>(&tsc[mg][lane * 4]);
                store_tile16(reinterpret_cast<u32x4*>(
                    Hp + ((size_t)(((t + 1) & 1) * 4 + mg) * 32 + bid) * 256 + lane * 4), tv);
                if (lane == 0) store_flag(flag_my, (unsigned int)(t + 2));  // no drain
            }
            // out stores (plain, cached) — off the critical path
#pragma unroll
            for (int r = 0; r < 4; ++r) {
                int b = mg * 16 + quad * 4 + r;
                out[(size_t)b * (1024 * 512) + (size_t)t * 512 + jg] = h_reg[r];
            }
            if (t < 1023) {
                // prefetch next step's x projections; complete during next wait
                const unsigned short* Xt = X + (size_t)(t + 1) * (64 * 1536);
#pragma unroll
                for (int r = 0; r < 4; ++r) {
                    int b = mg * 16 + quad * 4 + r;
#pragma unroll
                    for (int g = 0; g < 3; ++g)
                        xv[g][r] = bf2f(Xt[b * 1536 + g * 512 + jg]);
                }
            } else {
#pragma unroll
                for (int r = 0; r < 4; ++r) {
                    int b = mg * 16 + quad * 4 + r;
                    out[(size_t)(64 * 1024 * 512) + b * 512 + jg] = h_reg[r];
                }
            }
        }
    }
}

// ---------------------------------------------------------------- host
extern "C" void kernel_launch(void* const* d_in, const int* in_sizes, int n_in,
                              void* d_out, int out_size, void* d_ws, size_t ws_size,
                              hipStream_t stream) {
    const float* inputs = (const float*)d_in[0];
    const float* h0     = (const float*)d_in[1];
    const float* w_ir   = (const float*)d_in[2];
    const float* w_iz   = (const float*)d_in[3];
    const float* w_in   = (const float*)d_in[4];
    const float* b_ir   = (const float*)d_in[5];
    const float* b_iz   = (const float*)d_in[6];
    const float* b_in   = (const float*)d_in[7];
    const float* w_hr   = (const float*)d_in[8];
    const float* w_hz   = (const float*)d_in[9];
    const float* w_hn   = (const float*)d_in[10];
    const float* b_hr   = (const float*)d_in[11];
    const float* b_hz   = (const float*)d_in[12];
    const float* b_hn   = (const float*)d_in[13];
    float* out = (float*)d_out;

    // ws layout (16B aligned)
    char* wsb = (char*)d_ws;
    unsigned short* X     = (unsigned short*)(wsb);              // 201326592 B
    unsigned short* Abf   = (unsigned short*)(wsb + 201326592);  //  33554432 B
    unsigned short* Wx    = (unsigned short*)(wsb + 234881024);  //    786432 B
    unsigned short* Wh    = (unsigned short*)(wsb + 235667456);  //   1572864 B
    float*          biasx = (float*)        (wsb + 237240320);   //      6144 B
    unsigned int*   Hp    = (unsigned int*) (wsb + 237246464);   //    262144 B
    unsigned int*   flags = (unsigned int*) (wsb + 237508608);   //     16384 B (end 237524992)

    pack_inputs<<<16384, 256, 0, stream>>>(inputs, Abf);
    pack_weights<<<3072, 256, 0, stream>>>(w_ir, w_iz, w_in, b_ir, b_iz, b_in,
                                           w_hr, w_hz, w_hn, b_hr, b_hz, Wx, Wh, biasx, Hp, flags);
    xproj_gemm<<<dim3(1024, 24), 256, 0, stream>>>(Abf, Wx, biasx, X);
    gru_scan<<<32, 512, 0, stream>>>(X, Wh, h0, b_hn, Hp, flags, out);
}